// Round 16
// baseline (132.036 us; speedup 1.0000x reference)
//
#include <hip/hip_runtime.h>
#include <math.h>

#define LL 1024
#define DD 512
#define NB 8
#define KTOP 20
#define SZ (8 * 512 * 1024)  // elems per [B,D,L] plane

typedef __attribute__((ext_vector_type(8))) short bf16x8;
typedef __attribute__((ext_vector_type(4))) float f32x4;
typedef __attribute__((ext_vector_type(4))) int i32x4;

__device__ __forceinline__ unsigned short f2bf(float f) {
  union { float f; unsigned u; } v; v.f = f;
  unsigned r = v.u + 0x7FFFu + ((v.u >> 16) & 1u);
  return (unsigned short)(r >> 16);
}
__device__ __forceinline__ float bf2f(unsigned short u) {
  union { unsigned u; float f; } v; v.u = ((unsigned)u) << 16;
  return v.f;
}

// async global->LDS, 16B per lane; dest must be wave-uniform base + lane*16
__device__ __forceinline__ void gload16(const void* g, void* l) {
  __builtin_amdgcn_global_load_lds(
      (const __attribute__((address_space(1))) unsigned int*)g,
      (__attribute__((address_space(3))) unsigned int*)l, 16, 0, 0);
}

// ======== fused prep: transpose x -> xbT bf16 + xb bf16 ; pack weights ========
__global__ __launch_bounds__(256) void k_prep(const float* __restrict__ x,
                                              unsigned short* __restrict__ xbT,
                                              unsigned short* __restrict__ xb,
                                              const float* __restrict__ Wq,
                                              const float* __restrict__ Wk,
                                              const float* __restrict__ Wv,
                                              const float* __restrict__ W1,
                                              const float* __restrict__ W2,
                                              const float* __restrict__ bq,
                                              const float* __restrict__ bk,
                                              const float* __restrict__ bv,
                                              unsigned short* __restrict__ WqkvT,
                                              unsigned short* __restrict__ W1T,
                                              unsigned short* __restrict__ W2T,
                                              float* __restrict__ bqkv) {
  __shared__ float T[64][65];
  int bid = blockIdx.x;
  int tid = threadIdx.x;
  int lane = tid & 63, r4 = tid >> 6;
  if (bid < 1024) {  // transpose tile
    int b = bid >> 7, c0 = ((bid >> 4) & 7) * 64, t0 = (bid & 15) * 64;
#pragma unroll
    for (int it = 0; it < 16; ++it) {
      int tl = it * 4 + r4;
      T[lane][tl] = x[((size_t)b * LL + t0 + tl) * DD + c0 + lane];
    }
    __syncthreads();
#pragma unroll
    for (int it = 0; it < 16; ++it) {
      int cl = it * 4 + r4;
      xbT[((size_t)b * DD + c0 + cl) * LL + t0 + lane] = f2bf(T[cl][lane]);
    }
    int tl2 = tid >> 2, cq = (tid & 3) * 16;
    unsigned short* dxb = xb + ((size_t)b * LL + t0 + tl2) * DD + c0 + cq;
#pragma unroll
    for (int j = 0; j < 16; j += 4) {
      ushort4 u;
      u.x = f2bf(T[cq + j][tl2]);
      u.y = f2bf(T[cq + j + 1][tl2]);
      u.z = f2bf(T[cq + j + 2][tl2]);
      u.w = f2bf(T[cq + j + 3][tl2]);
      *(ushort4*)&dxb[j] = u;
    }
  } else {  // weight pack tile
    int pid = bid - 1024;
    int z = pid >> 6, n0 = ((pid >> 3) & 7) * 64, k0 = (pid & 7) * 64;
    const float* W = (z == 0) ? Wq : (z == 1) ? Wk : (z == 2) ? Wv : (z == 3) ? W1 : W2;
    unsigned short* dst = (z == 0) ? WqkvT
                        : (z == 1) ? (WqkvT + 512 * 512)
                        : (z == 2) ? (WqkvT + 1024 * 512)
                        : (z == 3) ? W1T : W2T;
#pragma unroll
    for (int it = 0; it < 16; ++it) {
      int kl = it * 4 + r4;
      T[lane][kl] = W[(size_t)(k0 + kl) * DD + n0 + lane];
    }
    __syncthreads();
    int n = tid >> 2, kq = (tid & 3) * 16;
    unsigned short* d = dst + (size_t)(n0 + n) * DD + k0 + kq;
#pragma unroll
    for (int j = 0; j < 16; j += 4) {
      ushort4 u;
      u.x = f2bf(T[n][kq + j]);
      u.y = f2bf(T[n][kq + j + 1]);
      u.z = f2bf(T[n][kq + j + 2]);
      u.w = f2bf(T[n][kq + j + 3]);
      *(ushort4*)&d[j] = u;
    }
    if (z == 4 && n0 == 0 && k0 == 0) {
      for (int i = tid; i < 1536; i += 256) {
        const float* s = (i < 512) ? bq : (i < 1024) ? bk : bv;
        bqkv[i] = s[i & 511];
      }
    }
  }
}

// ======== MFMA GEMM: C[M,N] = A[M,512] @ B^T[N,512], BM x 128 tile ========
// MODE 0: bias; out bf16 chan-major (3 planes Q/K/V contiguous)
// MODE 1 (BM=64): bias+relu; out bf16 token-major (h1)
// MODE 2 (BM=64): bias+residual(resbT bf16 chan-major); out f32 chan-major
template <int MODE, int BM>
__global__ __launch_bounds__(256) void k_mfma(const unsigned short* __restrict__ Aptr,
                                              const unsigned short* __restrict__ Bt,
                                              const float* __restrict__ bias,
                                              const unsigned short* __restrict__ resbT,
                                              unsigned short* __restrict__ outU,
                                              float* __restrict__ outF, int gx) {
  constexpr int MI = BM / 32;
  __shared__ char smem[(BM + 128) * 64 * 2 + (BM == 128 ? 2048 : 0)];
  unsigned short* As = (unsigned short*)smem;            // [BM][64]
  unsigned short* Bs = (unsigned short*)(smem + BM * 128);
  float* Cs = (float*)smem;

  int tid = threadIdx.x;
  int lane = tid & 63, wid = tid >> 6;
  int wr = wid & 1, wc = wid >> 1;

  int nwg = gridDim.x;
  int wg = blockIdx.x;
  int swz = (wg & 7) * (nwg >> 3) + (wg >> 3);
  int bix = swz % gx, biy = swz / gx;
  int n0 = bix * 128, m0 = biy * BM;
  int b = m0 >> 10, t0 = m0 & (LL - 1);

  f32x4 acc[MI][4];
#pragma unroll
  for (int i = 0; i < MI; ++i)
#pragma unroll
    for (int j = 0; j < 4; ++j) acc[i][j] = (f32x4){0.f, 0.f, 0.f, 0.f};

  int srow = tid >> 3, sq = tid & 7;

  for (int k0 = 0; k0 < 512; k0 += 64) {
#pragma unroll
    for (int p = 0; p < MI; ++p) {
      int r = srow + p * 32;
      int dq = sq ^ (r & 7);
      gload16(Aptr + (size_t)(m0 + r) * 512 + k0 + dq * 8, &As[r * 64 + sq * 8]);
    }
#pragma unroll
    for (int p = 0; p < 4; ++p) {
      int r = srow + p * 32;
      int dq = sq ^ (r & 7);
      gload16(Bt + (size_t)(n0 + r) * 512 + k0 + dq * 8, &Bs[r * 64 + sq * 8]);
    }
    __syncthreads();
#pragma unroll
    for (int ks = 0; ks < 2; ++ks) {
      bf16x8 af[MI], bf[4];
      int fr = lane & 15, kq = lane >> 4;
#pragma unroll
      for (int mi = 0; mi < MI; ++mi) {
        int r = wr * (BM / 2) + mi * 16 + fr;
        af[mi] = *(bf16x8*)&As[r * 64 + ((ks * 4 + kq) ^ (r & 7)) * 8];
      }
#pragma unroll
      for (int ni = 0; ni < 4; ++ni) {
        int r = wc * 64 + ni * 16 + fr;
        bf[ni] = *(bf16x8*)&Bs[r * 64 + ((ks * 4 + kq) ^ (r & 7)) * 8];
      }
#pragma unroll
      for (int mi = 0; mi < MI; ++mi)
#pragma unroll
        for (int ni = 0; ni < 4; ++ni)
          acc[mi][ni] = __builtin_amdgcn_mfma_f32_16x16x32_bf16(af[mi], bf[ni], acc[mi][ni], 0, 0, 0);
    }
    __syncthreads();
  }

  if (MODE == 0) {
    const int LDc = BM + 4;
    for (int p = 0; p < 2; ++p) {
      __syncthreads();
      if (wc == p) {
#pragma unroll
        for (int mi = 0; mi < MI; ++mi)
#pragma unroll
          for (int ni = 0; ni < 4; ++ni) {
            int nl = ni * 16 + (lane & 15);
            int ml = wr * (BM / 2) + mi * 16 + (lane >> 4) * 4;
            *(f32x4*)&Cs[nl * LDc + ml] = acc[mi][ni];
          }
      }
      __syncthreads();
      {
        int n = tid >> 2, mq = tid & 3;
        int ng = n0 + p * 64 + n;
        float bv = bias[ng];
        int sel = ng >> 9;
        unsigned short* drow =
            outU + ((size_t)sel * NB * 512 + b * 512 + (ng & 511)) * LL + t0;
#pragma unroll
        for (int i = 0; i < BM / 16; ++i) {
          int m = mq * 4 + i * 16;
          float4 v = *(float4*)&Cs[n * LDc + m];
          ushort4 u;
          u.x = f2bf(v.x + bv); u.y = f2bf(v.y + bv);
          u.z = f2bf(v.z + bv); u.w = f2bf(v.w + bv);
          *(ushort4*)&drow[m] = u;
        }
      }
    }
  } else if (MODE == 2) {
    const int LDc = 68;  // [64 n][64 m + 4 pad]
    for (int p = 0; p < 2; ++p) {
      __syncthreads();
      {
        int n = tid >> 2, mq = tid & 3;
        const unsigned short* rrow =
            resbT + ((size_t)(b * 512) + n0 + p * 64 + n) * LL + t0;
#pragma unroll
        for (int i = 0; i < 4; ++i) {
          int m = mq * 16 + i * 4;
          ushort4 u = *(const ushort4*)&rrow[m];
          float4 v;
          v.x = bf2f(u.x); v.y = bf2f(u.y); v.z = bf2f(u.z); v.w = bf2f(u.w);
          *(float4*)&Cs[n * LDc + m] = v;
        }
      }
      __syncthreads();
      if (wc == p) {
#pragma unroll
        for (int mi = 0; mi < MI; ++mi)
#pragma unroll
          for (int ni = 0; ni < 4; ++ni) {
            int nl = ni * 16 + (lane & 15);
            int ml = wr * (BM / 2) + mi * 16 + (lane >> 4) * 4;
            f32x4 cur = *(f32x4*)&Cs[nl * LDc + ml];
            cur += acc[mi][ni];
            *(f32x4*)&Cs[nl * LDc + ml] = cur;
          }
      }
      __syncthreads();
      {
        int n = tid >> 2, mq = tid & 3;
        int ng = n0 + p * 64 + n;
        float bv = bias[ng];
        float* drow = outF + ((size_t)b * 512 + ng) * LL + t0;
#pragma unroll
        for (int i = 0; i < 4; ++i) {
          int m = mq * 16 + i * 4;
          float4 v = *(float4*)&Cs[n * LDc + m];
          v.x += bv; v.y += bv; v.z += bv; v.w += bv;
          *(float4*)&drow[m] = v;
        }
      }
    }
  } else {  // MODE 1: [64 m][64 n + pad], token-major bf16 + relu
    const int LDh = 68;
    for (int p = 0; p < 2; ++p) {
      __syncthreads();
      if (wc == p) {
#pragma unroll
        for (int mi = 0; mi < MI; ++mi)
#pragma unroll
          for (int ni = 0; ni < 4; ++ni) {
            int nl = ni * 16 + (lane & 15);
            int ml = wr * (BM / 2) + mi * 16 + (lane >> 4) * 4;
#pragma unroll
            for (int r = 0; r < 4; ++r) Cs[(ml + r) * LDh + nl] = acc[mi][ni][r];
          }
      }
      __syncthreads();
      {
        int m = tid >> 2, nh = tid & 3;
        unsigned short* drow =
            outU + (size_t)(m0 + m) * 512 + n0 + p * 64 + nh * 16;
#pragma unroll
        for (int c = 0; c < 4; ++c) {
          float4 v = *(float4*)&Cs[m * LDh + nh * 16 + c * 4];
          float4 bb = *(const float4*)&bias[n0 + p * 64 + nh * 16 + c * 4];
          v.x = fmaxf(v.x + bb.x, 0.f);
          v.y = fmaxf(v.y + bb.y, 0.f);
          v.z = fmaxf(v.z + bb.z, 0.f);
          v.w = fmaxf(v.w + bb.w, 0.f);
          ushort4 u;
          u.x = f2bf(v.x); u.y = f2bf(v.y); u.z = f2bf(v.z); u.w = f2bf(v.w);
          *(ushort4*)&drow[c * 4] = u;
        }
      }
    }
  }
}

// ======== autocorr: R15 (serial topk, launch_bounds(256,6)) ========
__global__ __launch_bounds__(256, 6) void k_autocorr(const unsigned short* __restrict__ Qbf,
                                                     const unsigned short* __restrict__ Kbf,
                                                     const unsigned short* __restrict__ Vbf,
                                                     const unsigned short* __restrict__ xbT,
                                                     unsigned short* __restrict__ xsbT) {
  __shared__ char sm[16672];
  unsigned* KshW = (unsigned*)sm;             // [2080] dw: 4 rows x 520
  float* Vs2 = (float*)(sm + 8320);           // [2048]: V + saturated tail
  float* wvs = (float*)(sm + 16512);          // [20]
  int*   wis = (int*)(sm + 16592);            // [20]
  float* Csp = (float*)sm;                    // [1056] alias Ksh rows 0-1 (dead)
  float* Cp  = (float*)(sm + 4224);           // [1024] alias Ksh rows 2-3 (dead)

  int tid = threadIdx.x;
  int lane = tid & 63, wave = tid >> 6;
  size_t base = (size_t)blockIdx.x * LL;

  // ---- stage: V (bf16->f32, saturated tail) + Ksh4 rows ----
  {
    ushort4 vv = *(const ushort4*)(Vbf + base + tid * 4);
    float4 vf;
    vf.x = bf2f(vv.x); vf.y = bf2f(vv.y); vf.z = bf2f(vv.z); vf.w = bf2f(vv.w);
    *(float4*)&Vs2[tid * 4] = vf;
    float vlast = bf2f(Vbf[base + 1023]);
    *(float4*)&Vs2[1024 + tid * 4] = make_float4(vlast, vlast, vlast, vlast);

    ushort4 kv = *(const ushort4*)(Kbf + base + tid * 4);
    unsigned w0 = (unsigned)kv.x | ((unsigned)kv.y << 16);
    unsigned w1 = (unsigned)kv.z | ((unsigned)kv.w << 16);
    unsigned wq = __shfl_up(w0, 1);
    unsigned wp = __shfl_up(w1, 1);
    if (lane == 0) {
      wq = *(const unsigned*)(Kbf + base + ((tid * 4 - 4) & (LL - 1)));
      wp = *(const unsigned*)(Kbf + base + ((tid * 4 - 2) & (LL - 1)));
    }
    int d = 8 + 2 * tid;
    uint2 u0; u0.x = w0;                      u0.y = w1;
    uint2 u1; u1.x = (wp >> 16) | (w0 << 16); u1.y = (w0 >> 16) | (w1 << 16);
    uint2 u2; u2.x = wp;                      u2.y = w0;
    uint2 u3; u3.x = (wq >> 16) | (wp << 16); u3.y = (wp >> 16) | (w0 << 16);
    *(uint2*)&KshW[d]        = u0;
    *(uint2*)&KshW[520 + d]  = u1;
    *(uint2*)&KshW[1040 + d] = u2;
    *(uint2*)&KshW[1560 + d] = u3;
    if (tid >= 224) {  // wrap prefix p in [-16,0): 4 rows x 8 dwords
      int q2 = tid - 224;
      int s = q2 >> 3, dd = q2 & 7;
      int p = 2 * dd - 16;
      unsigned short a = Kbf[base + ((p - s) & (LL - 1))];
      unsigned short b2 = Kbf[base + ((p + 1 - s) & (LL - 1))];
      KshW[s * 520 + dd] = (unsigned)a | ((unsigned)b2 << 16);
    }
  }
  __syncthreads();

  // ---- correlation via MFMA: 32 K-steps, A-frags from global ----
  f32x4 acc = (f32x4){0.f, 0.f, 0.f, 0.f};
  int fr = lane & 15, kq = lane >> 4;
  int g = wave;
  int srow = fr & 3, fp = fr >> 2;
  int aE = (256 * g + 16 * fr + 8 * kq) & (LL - 1);
  int bD0 = srow * 520 + 8 + 4 * kq - 2 * fp;
  const unsigned short* qp = Qbf + base;
#pragma unroll
  for (int ks = 0; ks < 32; ++ks) {
    bf16x8 av = *(const bf16x8*)(qp + aE);
    int bD = bD0 + 16 * ks;
    uint2 b01 = *(const uint2*)&KshW[bD];
    uint2 b23 = *(const uint2*)&KshW[bD + 2];
    union { unsigned u[4]; bf16x8 h; } ub;
    ub.u[0] = b01.x; ub.u[1] = b01.y; ub.u[2] = b23.x; ub.u[3] = b23.y;
    acc = __builtin_amdgcn_mfma_f32_16x16x32_bf16(av, ub.h, acc, 0, 0, 0);
    aE = (aE + 32) & (LL - 1);
  }
  __syncthreads();  // all Ksh reads done before Cp/Csp (aliases) are written
#pragma unroll
  for (int r = 0; r < 4; ++r) {
    int tau = 256 * g + 64 * kq + 16 * r + fr;
    Cp[tau ^ (((tau >> 6) & 3) << 4)] = acc[r];
  }
  __syncthreads();

  // ---- top-20 on wave 'sel' (direct-to-LDS, descending); others: pads ----
  int sel = blockIdx.x & 3;
  if (wave == sel) {
    float c0[16];
#pragma unroll
    for (int j = 0; j < 16; ++j) {
      int tau = 64 * j + lane;
      c0[j] = Cp[tau ^ (((tau >> 6) & 3) << 4)];
    }
    float lbest = c0[0];
    int lidx = 0;
#pragma unroll
    for (int m = 1; m < 16; ++m)
      if (c0[m] > lbest) { lbest = c0[m]; lidx = m; }

#pragma unroll 1
    for (int s = 0; s < KTOP; ++s) {
      float best = lbest;
      int bidx = 64 * lidx + lane;
#pragma unroll
      for (int off = 32; off; off >>= 1) {
        float v2 = __shfl_xor(best, off);
        int i2 = __shfl_xor(bidx, off);
        if (v2 > best || (v2 == best && i2 < bidx)) { best = v2; bidx = i2; }
      }
      if (lane == 0) { wvs[s] = best; wis[s] = bidx; }
      int kill = ((bidx & 63) == lane) ? (bidx >> 6) : -1;
#pragma unroll
      for (int m = 0; m < 16; ++m)
        if (m == kill) c0[m] = -3.0e38f;
      lbest = c0[0];
      lidx = 0;
#pragma unroll
      for (int m = 1; m < 16; ++m)
        if (c0[m] > lbest) { lbest = c0[m]; lidx = m; }
    }
    // wave-parallel softmax; extraction order is descending so mx = wvs[0]
    float mx = wvs[0];
    float e = (lane < KTOP) ? __expf(wvs[lane] - mx) : 0.f;
    float ssum = e;
#pragma unroll
    for (int off = 32; off; off >>= 1) ssum += __shfl_xor(ssum, off);
    if (lane < KTOP) wvs[lane] = e / ssum;
  } else {
    int ft = (wave < sel ? wave : wave - 1) * 64 + lane;  // 0..191
    if (ft < 16) Csp[ft] = 0.f;                   // front pad
    else if (ft < 32) Csp[1040 + ft - 16] = 0.f;  // back pad
  }
  __syncthreads();

  // ---- aggregate (saturated table, no clamp) + bf16 residual ----
  {
    float r[4];
#pragma unroll
    for (int i = 0; i < 4; ++i) r[i] = bf2f(xbT[base + tid + 256 * i]);
#pragma unroll
    for (int k = 0; k < KTOP; ++k) {
      float w = wvs[k];
      int wi = wis[k];
#pragma unroll
      for (int i = 0; i < 4; ++i) r[i] += w * Vs2[wi + tid + 256 * i];
    }
#pragma unroll
    for (int i = 0; i < 4; ++i) Csp[16 + tid + 256 * i] = r[i];
  }
  __syncthreads();

  // ---- series_decomp #1 -> bf16 chan-major ----
  {
    int t0 = tid * 4;
    float buf[28];
#pragma unroll
    for (int qd = 0; qd < 7; ++qd)
      *(float4*)&buf[qd * 4] = *(const float4*)&Csp[t0 + 4 + qd * 4];
    float s = 0.f;
#pragma unroll
    for (int m = 0; m < 25; ++m) s += buf[m];
    ushort4 o;
    o.x = f2bf(buf[12] - s * (1.0f / 25.0f));
    s += buf[25] - buf[0];
    o.y = f2bf(buf[13] - s * (1.0f / 25.0f));
    s += buf[26] - buf[1];
    o.z = f2bf(buf[14] - s * (1.0f / 25.0f));
    s += buf[27] - buf[2];
    o.w = f2bf(buf[15] - s * (1.0f / 25.0f));
    *(ushort4*)&xsbT[base + t0] = o;
  }
}

// ======== xsbT [c][t] bf16 -> xsb [t][c] bf16 ========
__global__ __launch_bounds__(256) void k_castT(const unsigned short* __restrict__ src,
                                               unsigned short* __restrict__ dst) {
  __shared__ unsigned short T[64][68];
  int b = blockIdx.z;
  int t0 = blockIdx.x * 64, c0 = blockIdx.y * 64;
  int tid = threadIdx.x;
  int lane = tid & 63, r4 = tid >> 6;
#pragma unroll
  for (int it = 0; it < 16; ++it) {
    int cl = it * 4 + r4;
    T[lane][cl] = src[((size_t)b * 512 + c0 + cl) * LL + t0 + lane];
  }
  __syncthreads();
  int tl = tid >> 2, cq = (tid & 3) * 16;
  unsigned short* d = dst + ((size_t)b * LL + t0 + tl) * 512 + c0 + cq;
#pragma unroll
  for (int j = 0; j < 16; j += 4) {
    ushort4 u;
    u.x = T[tl][cq + j]; u.y = T[tl][cq + j + 1];
    u.z = T[tl][cq + j + 2]; u.w = T[tl][cq + j + 3];
    *(ushort4*)&d[j] = u;
  }
}

// ======== final decomp: s2T [c][t] f32 -> out [t][c] f32 ========
#define DCH 32
__global__ __launch_bounds__(256) void k_decomp2T(const float* __restrict__ s2T,
                                                  float* __restrict__ out) {
  __shared__ float T[DCH][289];
  int b = blockIdx.z, c0 = blockIdx.y * DCH, t0 = blockIdx.x * 256;
  int tid = threadIdx.x;
  {
    int row = tid >> 3, j0 = tid & 7;
    const float* src = s2T + ((size_t)b * 512 + c0 + row) * LL;
#pragma unroll
    for (int i = 0; i < 9; ++i) {
      int col = (j0 + i * 8) * 4;
      int t = t0 - 16 + col;
      float4 v = make_float4(0.f, 0.f, 0.f, 0.f);
      if (t >= 0 && t < LL) v = *(const float4*)&src[t];
      *(float4*)&T[row][col] = v;
    }
  }
  __syncthreads();
  int c = tid & 31, tg = tid >> 5;
  float sum = 0.f;
  int basec = tg * 32 + 4;
#pragma unroll
  for (int j = 0; j < 25; ++j) sum += T[c][basec + j];
  float* orow = out + ((size_t)b * LL + t0 + tg * 32) * 512 + c0 + c;
#pragma unroll 1
  for (int s = 0; s < 32; ++s) {
    float center = T[c][tg * 32 + 16 + s];
    orow[(size_t)s * 512] = center - sum * (1.f / 25.f);
    sum += T[c][basec + 25 + s] - T[c][basec + s];
  }
}

// ======== launch ========
extern "C" void kernel_launch(void* const* d_in, const int* in_sizes, int n_in,
                              void* d_out, int out_size, void* d_ws, size_t ws_size,
                              hipStream_t stream) {
  const float* x  = (const float*)d_in[0];
  const float* Wq = (const float*)d_in[1];
  const float* bq = (const float*)d_in[2];
  const float* Wk = (const float*)d_in[3];
  const float* bk = (const float*)d_in[4];
  const float* Wv = (const float*)d_in[5];
  const float* bv = (const float*)d_in[6];
  const float* W1 = (const float*)d_in[7];
  const float* b1 = (const float*)d_in[8];
  const float* W2 = (const float*)d_in[9];
  const float* b2 = (const float*)d_in[10];
  float* out = (float*)d_out;
  char* w = (char*)d_ws;

  unsigned short* xbT   = (unsigned short*)w;
  unsigned short* Qbf   = (unsigned short*)(w + (size_t)SZ * 4);
  unsigned short* Kbf   = Qbf + SZ;
  unsigned short* Vbf   = Kbf + SZ;
  unsigned short* WqkvT = (unsigned short*)(w + (size_t)SZ * 12);
  unsigned short* W1T   = WqkvT + 1536 * 512;
  unsigned short* W2T   = W1T + 512 * 512;
  float* bqkv           = (float*)(W2T + 512 * 512);
  unsigned short* xb    = (unsigned short*)(w + (size_t)SZ * 14);
  unsigned short* h1    = (unsigned short*)w;
  unsigned short* xsb   = (unsigned short*)(w + (size_t)SZ * 2);
  unsigned short* xsbT  = Qbf;
  float* s2T            = (float*)(w + (size_t)SZ * 6);

  k_prep<<<dim3(1344), 256, 0, stream>>>(x, xbT, xb, Wq, Wk, Wv, W1, W2,
                                         bq, bk, bv, WqkvT, W1T, W2T, bqkv);

  k_mfma<0, 64><<<dim3(1536), 256, 0, stream>>>(xb, WqkvT, bqkv, nullptr, Qbf, nullptr, 12);

  k_autocorr<<<dim3(NB * DD), 256, 0, stream>>>(Qbf, Kbf, Vbf, xbT, xsbT);

  k_castT<<<dim3(16, 8, NB), 256, 0, stream>>>(xsbT, xsb);

  k_mfma<1, 64><<<dim3(512), 256, 0, stream>>>(xsb, W1T, b1, nullptr, h1, nullptr, 4);
  k_mfma<2, 64><<<dim3(512), 256, 0, stream>>>(h1, W2T, b2, xsbT, nullptr, s2T, 4);

  k_decomp2T<<<dim3(4, 16, NB), 256, 0, stream>>>(s2T, out);
}

// Round 17
// 124.292 us; speedup vs baseline: 1.0623x; 1.0623x over previous
//
#include <hip/hip_runtime.h>
#include <math.h>

#define LL 1024
#define DD 512
#define NB 8
#define KTOP 20
#define SZ (8 * 512 * 1024)  // elems per [B,D,L] plane

typedef __attribute__((ext_vector_type(8))) short bf16x8;
typedef __attribute__((ext_vector_type(4))) float f32x4;
typedef __attribute__((ext_vector_type(4))) int i32x4;

__device__ __forceinline__ unsigned short f2bf(float f) {
  union { float f; unsigned u; } v; v.f = f;
  unsigned r = v.u + 0x7FFFu + ((v.u >> 16) & 1u);
  return (unsigned short)(r >> 16);
}
__device__ __forceinline__ float bf2f(unsigned short u) {
  union { unsigned u; float f; } v; v.u = ((unsigned)u) << 16;
  return v.f;
}

// async global->LDS, 16B per lane; dest must be wave-uniform base + lane*16
__device__ __forceinline__ void gload16(const void* g, void* l) {
  __builtin_amdgcn_global_load_lds(
      (const __attribute__((address_space(1))) unsigned int*)g,
      (__attribute__((address_space(3))) unsigned int*)l, 16, 0, 0);
}

// ======== fused prep: transpose x -> xbT bf16 + xb bf16 ; pack weights ========
__global__ __launch_bounds__(256) void k_prep(const float* __restrict__ x,
                                              unsigned short* __restrict__ xbT,
                                              unsigned short* __restrict__ xb,
                                              const float* __restrict__ Wq,
                                              const float* __restrict__ Wk,
                                              const float* __restrict__ Wv,
                                              const float* __restrict__ W1,
                                              const float* __restrict__ W2,
                                              const float* __restrict__ bq,
                                              const float* __restrict__ bk,
                                              const float* __restrict__ bv,
                                              unsigned short* __restrict__ WqkvT,
                                              unsigned short* __restrict__ W1T,
                                              unsigned short* __restrict__ W2T,
                                              float* __restrict__ bqkv) {
  __shared__ float T[64][65];
  int bid = blockIdx.x;
  int tid = threadIdx.x;
  int lane = tid & 63, r4 = tid >> 6;
  if (bid < 1024) {  // transpose tile
    int b = bid >> 7, c0 = ((bid >> 4) & 7) * 64, t0 = (bid & 15) * 64;
#pragma unroll
    for (int it = 0; it < 16; ++it) {
      int tl = it * 4 + r4;
      T[lane][tl] = x[((size_t)b * LL + t0 + tl) * DD + c0 + lane];
    }
    __syncthreads();
#pragma unroll
    for (int it = 0; it < 16; ++it) {
      int cl = it * 4 + r4;
      xbT[((size_t)b * DD + c0 + cl) * LL + t0 + lane] = f2bf(T[cl][lane]);
    }
    int tl2 = tid >> 2, cq = (tid & 3) * 16;
    unsigned short* dxb = xb + ((size_t)b * LL + t0 + tl2) * DD + c0 + cq;
#pragma unroll
    for (int j = 0; j < 16; j += 4) {
      ushort4 u;
      u.x = f2bf(T[cq + j][tl2]);
      u.y = f2bf(T[cq + j + 1][tl2]);
      u.z = f2bf(T[cq + j + 2][tl2]);
      u.w = f2bf(T[cq + j + 3][tl2]);
      *(ushort4*)&dxb[j] = u;
    }
  } else {  // weight pack tile
    int pid = bid - 1024;
    int z = pid >> 6, n0 = ((pid >> 3) & 7) * 64, k0 = (pid & 7) * 64;
    const float* W = (z == 0) ? Wq : (z == 1) ? Wk : (z == 2) ? Wv : (z == 3) ? W1 : W2;
    unsigned short* dst = (z == 0) ? WqkvT
                        : (z == 1) ? (WqkvT + 512 * 512)
                        : (z == 2) ? (WqkvT + 1024 * 512)
                        : (z == 3) ? W1T : W2T;
#pragma unroll
    for (int it = 0; it < 16; ++it) {
      int kl = it * 4 + r4;
      T[lane][kl] = W[(size_t)(k0 + kl) * DD + n0 + lane];
    }
    __syncthreads();
    int n = tid >> 2, kq = (tid & 3) * 16;
    unsigned short* d = dst + (size_t)(n0 + n) * DD + k0 + kq;
#pragma unroll
    for (int j = 0; j < 16; j += 4) {
      ushort4 u;
      u.x = f2bf(T[n][kq + j]);
      u.y = f2bf(T[n][kq + j + 1]);
      u.z = f2bf(T[n][kq + j + 2]);
      u.w = f2bf(T[n][kq + j + 3]);
      *(ushort4*)&d[j] = u;
    }
    if (z == 4 && n0 == 0 && k0 == 0) {
      for (int i = tid; i < 1536; i += 256) {
        const float* s = (i < 512) ? bq : (i < 1024) ? bk : bv;
        bqkv[i] = s[i & 511];
      }
    }
  }
}

// ======== MFMA GEMM: C[M,N] = A[M,512] @ B^T[N,512], BM x 128 tile ========
// MODE 0 (BM=128): bias; out bf16 chan-major (3 planes Q/K/V contiguous)
// MODE 1 (BM=64):  bias+relu; out bf16 token-major (h1)
// MODE 2 (BM=64):  bias+residual(resbT bf16 chan-major); out bf16 chan-major
template <int MODE, int BM>
__global__ __launch_bounds__(256) void k_mfma(const unsigned short* __restrict__ Aptr,
                                              const unsigned short* __restrict__ Bt,
                                              const float* __restrict__ bias,
                                              const unsigned short* __restrict__ resbT,
                                              unsigned short* __restrict__ outU,
                                              float* __restrict__ outF, int gx) {
  constexpr int MI = BM / 32;
  __shared__ char smem[(BM + 128) * 64 * 2 + (BM == 128 ? 2048 : 0)];
  unsigned short* As = (unsigned short*)smem;            // [BM][64]
  unsigned short* Bs = (unsigned short*)(smem + BM * 128);
  float* Cs = (float*)smem;

  int tid = threadIdx.x;
  int lane = tid & 63, wid = tid >> 6;
  int wr = wid & 1, wc = wid >> 1;

  int nwg = gridDim.x;
  int wg = blockIdx.x;
  int swz = (wg & 7) * (nwg >> 3) + (wg >> 3);
  int bix = swz % gx, biy = swz / gx;
  int n0 = bix * 128, m0 = biy * BM;
  int b = m0 >> 10, t0 = m0 & (LL - 1);

  f32x4 acc[MI][4];
#pragma unroll
  for (int i = 0; i < MI; ++i)
#pragma unroll
    for (int j = 0; j < 4; ++j) acc[i][j] = (f32x4){0.f, 0.f, 0.f, 0.f};

  int srow = tid >> 3, sq = tid & 7;

  for (int k0 = 0; k0 < 512; k0 += 64) {
#pragma unroll
    for (int p = 0; p < MI; ++p) {
      int r = srow + p * 32;
      int dq = sq ^ (r & 7);
      gload16(Aptr + (size_t)(m0 + r) * 512 + k0 + dq * 8, &As[r * 64 + sq * 8]);
    }
#pragma unroll
    for (int p = 0; p < 4; ++p) {
      int r = srow + p * 32;
      int dq = sq ^ (r & 7);
      gload16(Bt + (size_t)(n0 + r) * 512 + k0 + dq * 8, &Bs[r * 64 + sq * 8]);
    }
    __syncthreads();
#pragma unroll
    for (int ks = 0; ks < 2; ++ks) {
      bf16x8 af[MI], bf[4];
      int fr = lane & 15, kq = lane >> 4;
#pragma unroll
      for (int mi = 0; mi < MI; ++mi) {
        int r = wr * (BM / 2) + mi * 16 + fr;
        af[mi] = *(bf16x8*)&As[r * 64 + ((ks * 4 + kq) ^ (r & 7)) * 8];
      }
#pragma unroll
      for (int ni = 0; ni < 4; ++ni) {
        int r = wc * 64 + ni * 16 + fr;
        bf[ni] = *(bf16x8*)&Bs[r * 64 + ((ks * 4 + kq) ^ (r & 7)) * 8];
      }
#pragma unroll
      for (int mi = 0; mi < MI; ++mi)
#pragma unroll
        for (int ni = 0; ni < 4; ++ni)
          acc[mi][ni] = __builtin_amdgcn_mfma_f32_16x16x32_bf16(af[mi], bf[ni], acc[mi][ni], 0, 0, 0);
    }
    __syncthreads();
  }

  if (MODE == 0) {
    const int LDc = BM + 4;
    for (int p = 0; p < 2; ++p) {
      __syncthreads();
      if (wc == p) {
#pragma unroll
        for (int mi = 0; mi < MI; ++mi)
#pragma unroll
          for (int ni = 0; ni < 4; ++ni) {
            int nl = ni * 16 + (lane & 15);
            int ml = wr * (BM / 2) + mi * 16 + (lane >> 4) * 4;
            *(f32x4*)&Cs[nl * LDc + ml] = acc[mi][ni];
          }
      }
      __syncthreads();
      {
        int n = tid >> 2, mq = tid & 3;
        int ng = n0 + p * 64 + n;
        float bv = bias[ng];
        int sel = ng >> 9;
        unsigned short* drow =
            outU + ((size_t)sel * NB * 512 + b * 512 + (ng & 511)) * LL + t0;
#pragma unroll
        for (int i = 0; i < BM / 16; ++i) {
          int m = mq * 4 + i * 16;
          float4 v = *(float4*)&Cs[n * LDc + m];
          ushort4 u;
          u.x = f2bf(v.x + bv); u.y = f2bf(v.y + bv);
          u.z = f2bf(v.z + bv); u.w = f2bf(v.w + bv);
          *(ushort4*)&drow[m] = u;
        }
      }
    }
  } else if (MODE == 2) {
    const int LDc = 68;  // [64 n][64 m + 4 pad]
    for (int p = 0; p < 2; ++p) {
      __syncthreads();
      {
        int n = tid >> 2, mq = tid & 3;
        const unsigned short* rrow =
            resbT + ((size_t)(b * 512) + n0 + p * 64 + n) * LL + t0;
#pragma unroll
        for (int i = 0; i < 4; ++i) {
          int m = mq * 16 + i * 4;
          ushort4 u = *(const ushort4*)&rrow[m];
          float4 v;
          v.x = bf2f(u.x); v.y = bf2f(u.y); v.z = bf2f(u.z); v.w = bf2f(u.w);
          *(float4*)&Cs[n * LDc + m] = v;
        }
      }
      __syncthreads();
      if (wc == p) {
#pragma unroll
        for (int mi = 0; mi < MI; ++mi)
#pragma unroll
          for (int ni = 0; ni < 4; ++ni) {
            int nl = ni * 16 + (lane & 15);
            int ml = wr * (BM / 2) + mi * 16 + (lane >> 4) * 4;
            f32x4 cur = *(f32x4*)&Cs[nl * LDc + ml];
            cur += acc[mi][ni];
            *(f32x4*)&Cs[nl * LDc + ml] = cur;
          }
      }
      __syncthreads();
      {
        int n = tid >> 2, mq = tid & 3;
        int ng = n0 + p * 64 + n;
        float bv = bias[ng];
        unsigned short* drow = outU + ((size_t)b * 512 + ng) * LL + t0;
#pragma unroll
        for (int i = 0; i < 4; ++i) {
          int m = mq * 16 + i * 4;
          float4 v = *(float4*)&Cs[n * LDc + m];
          ushort4 u;
          u.x = f2bf(v.x + bv); u.y = f2bf(v.y + bv);
          u.z = f2bf(v.z + bv); u.w = f2bf(v.w + bv);
          *(ushort4*)&drow[m] = u;
        }
      }
    }
  } else {  // MODE 1: [64 m][64 n + pad], token-major bf16 + relu
    const int LDh = 68;
    for (int p = 0; p < 2; ++p) {
      __syncthreads();
      if (wc == p) {
#pragma unroll
        for (int mi = 0; mi < MI; ++mi)
#pragma unroll
          for (int ni = 0; ni < 4; ++ni) {
            int nl = ni * 16 + (lane & 15);
            int ml = wr * (BM / 2) + mi * 16 + (lane >> 4) * 4;
#pragma unroll
            for (int r = 0; r < 4; ++r) Cs[(ml + r) * LDh + nl] = acc[mi][ni][r];
          }
      }
      __syncthreads();
      {
        int m = tid >> 2, nh = tid & 3;
        unsigned short* drow =
            outU + (size_t)(m0 + m) * 512 + n0 + p * 64 + nh * 16;
#pragma unroll
        for (int c = 0; c < 4; ++c) {
          float4 v = *(float4*)&Cs[m * LDh + nh * 16 + c * 4];
          float4 bb = *(const float4*)&bias[n0 + p * 64 + nh * 16 + c * 4];
          v.x = fmaxf(v.x + bb.x, 0.f);
          v.y = fmaxf(v.y + bb.y, 0.f);
          v.z = fmaxf(v.z + bb.z, 0.f);
          v.w = fmaxf(v.w + bb.w, 0.f);
          ushort4 u;
          u.x = f2bf(v.x); u.y = f2bf(v.y); u.z = f2bf(v.z); u.w = f2bf(v.w);
          *(ushort4*)&drow[c * 4] = u;
        }
      }
    }
  }
}

// ======== autocorr: R15 (serial topk, launch_bounds(256,6)) ========
__global__ __launch_bounds__(256, 6) void k_autocorr(const unsigned short* __restrict__ Qbf,
                                                     const unsigned short* __restrict__ Kbf,
                                                     const unsigned short* __restrict__ Vbf,
                                                     const unsigned short* __restrict__ xbT,
                                                     unsigned short* __restrict__ xsbT) {
  __shared__ char sm[16672];
  unsigned* KshW = (unsigned*)sm;             // [2080] dw: 4 rows x 520
  float* Vs2 = (float*)(sm + 8320);           // [2048]: V + saturated tail
  float* wvs = (float*)(sm + 16512);          // [20]
  int*   wis = (int*)(sm + 16592);            // [20]
  float* Csp = (float*)sm;                    // [1056] alias Ksh rows 0-1 (dead)
  float* Cp  = (float*)(sm + 4224);           // [1024] alias Ksh rows 2-3 (dead)

  int tid = threadIdx.x;
  int lane = tid & 63, wave = tid >> 6;
  size_t base = (size_t)blockIdx.x * LL;

  // ---- stage: V (bf16->f32, saturated tail) + Ksh4 rows ----
  {
    ushort4 vv = *(const ushort4*)(Vbf + base + tid * 4);
    float4 vf;
    vf.x = bf2f(vv.x); vf.y = bf2f(vv.y); vf.z = bf2f(vv.z); vf.w = bf2f(vv.w);
    *(float4*)&Vs2[tid * 4] = vf;
    float vlast = bf2f(Vbf[base + 1023]);
    *(float4*)&Vs2[1024 + tid * 4] = make_float4(vlast, vlast, vlast, vlast);

    ushort4 kv = *(const ushort4*)(Kbf + base + tid * 4);
    unsigned w0 = (unsigned)kv.x | ((unsigned)kv.y << 16);
    unsigned w1 = (unsigned)kv.z | ((unsigned)kv.w << 16);
    unsigned wq = __shfl_up(w0, 1);
    unsigned wp = __shfl_up(w1, 1);
    if (lane == 0) {
      wq = *(const unsigned*)(Kbf + base + ((tid * 4 - 4) & (LL - 1)));
      wp = *(const unsigned*)(Kbf + base + ((tid * 4 - 2) & (LL - 1)));
    }
    int d = 8 + 2 * tid;
    uint2 u0; u0.x = w0;                      u0.y = w1;
    uint2 u1; u1.x = (wp >> 16) | (w0 << 16); u1.y = (w0 >> 16) | (w1 << 16);
    uint2 u2; u2.x = wp;                      u2.y = w0;
    uint2 u3; u3.x = (wq >> 16) | (wp << 16); u3.y = (wp >> 16) | (w0 << 16);
    *(uint2*)&KshW[d]        = u0;
    *(uint2*)&KshW[520 + d]  = u1;
    *(uint2*)&KshW[1040 + d] = u2;
    *(uint2*)&KshW[1560 + d] = u3;
    if (tid >= 224) {  // wrap prefix p in [-16,0): 4 rows x 8 dwords
      int q2 = tid - 224;
      int s = q2 >> 3, dd = q2 & 7;
      int p = 2 * dd - 16;
      unsigned short a = Kbf[base + ((p - s) & (LL - 1))];
      unsigned short b2 = Kbf[base + ((p + 1 - s) & (LL - 1))];
      KshW[s * 520 + dd] = (unsigned)a | ((unsigned)b2 << 16);
    }
  }
  __syncthreads();

  // ---- correlation via MFMA: 32 K-steps, A-frags from global ----
  f32x4 acc = (f32x4){0.f, 0.f, 0.f, 0.f};
  int fr = lane & 15, kq = lane >> 4;
  int g = wave;
  int srow = fr & 3, fp = fr >> 2;
  int aE = (256 * g + 16 * fr + 8 * kq) & (LL - 1);
  int bD0 = srow * 520 + 8 + 4 * kq - 2 * fp;
  const unsigned short* qp = Qbf + base;
#pragma unroll
  for (int ks = 0; ks < 32; ++ks) {
    bf16x8 av = *(const bf16x8*)(qp + aE);
    int bD = bD0 + 16 * ks;
    uint2 b01 = *(const uint2*)&KshW[bD];
    uint2 b23 = *(const uint2*)&KshW[bD + 2];
    union { unsigned u[4]; bf16x8 h; } ub;
    ub.u[0] = b01.x; ub.u[1] = b01.y; ub.u[2] = b23.x; ub.u[3] = b23.y;
    acc = __builtin_amdgcn_mfma_f32_16x16x32_bf16(av, ub.h, acc, 0, 0, 0);
    aE = (aE + 32) & (LL - 1);
  }
  __syncthreads();  // all Ksh reads done before Cp/Csp (aliases) are written
#pragma unroll
  for (int r = 0; r < 4; ++r) {
    int tau = 256 * g + 64 * kq + 16 * r + fr;
    Cp[tau ^ (((tau >> 6) & 3) << 4)] = acc[r];
  }
  __syncthreads();

  // ---- top-20 on wave 'sel' (direct-to-LDS, descending); others: pads ----
  int sel = blockIdx.x & 3;
  if (wave == sel) {
    float c0[16];
#pragma unroll
    for (int j = 0; j < 16; ++j) {
      int tau = 64 * j + lane;
      c0[j] = Cp[tau ^ (((tau >> 6) & 3) << 4)];
    }
    float lbest = c0[0];
    int lidx = 0;
#pragma unroll
    for (int m = 1; m < 16; ++m)
      if (c0[m] > lbest) { lbest = c0[m]; lidx = m; }

#pragma unroll 1
    for (int s = 0; s < KTOP; ++s) {
      float best = lbest;
      int bidx = 64 * lidx + lane;
#pragma unroll
      for (int off = 32; off; off >>= 1) {
        float v2 = __shfl_xor(best, off);
        int i2 = __shfl_xor(bidx, off);
        if (v2 > best || (v2 == best && i2 < bidx)) { best = v2; bidx = i2; }
      }
      if (lane == 0) { wvs[s] = best; wis[s] = bidx; }
      int kill = ((bidx & 63) == lane) ? (bidx >> 6) : -1;
#pragma unroll
      for (int m = 0; m < 16; ++m)
        if (m == kill) c0[m] = -3.0e38f;
      lbest = c0[0];
      lidx = 0;
#pragma unroll
      for (int m = 1; m < 16; ++m)
        if (c0[m] > lbest) { lbest = c0[m]; lidx = m; }
    }
    // wave-parallel softmax; extraction order is descending so mx = wvs[0]
    float mx = wvs[0];
    float e = (lane < KTOP) ? __expf(wvs[lane] - mx) : 0.f;
    float ssum = e;
#pragma unroll
    for (int off = 32; off; off >>= 1) ssum += __shfl_xor(ssum, off);
    if (lane < KTOP) wvs[lane] = e / ssum;
  } else {
    int ft = (wave < sel ? wave : wave - 1) * 64 + lane;  // 0..191
    if (ft < 16) Csp[ft] = 0.f;                   // front pad
    else if (ft < 32) Csp[1040 + ft - 16] = 0.f;  // back pad
  }
  __syncthreads();

  // ---- aggregate (saturated table, no clamp) + bf16 residual ----
  {
    float r[4];
#pragma unroll
    for (int i = 0; i < 4; ++i) r[i] = bf2f(xbT[base + tid + 256 * i]);
#pragma unroll
    for (int k = 0; k < KTOP; ++k) {
      float w = wvs[k];
      int wi = wis[k];
#pragma unroll
      for (int i = 0; i < 4; ++i) r[i] += w * Vs2[wi + tid + 256 * i];
    }
#pragma unroll
    for (int i = 0; i < 4; ++i) Csp[16 + tid + 256 * i] = r[i];
  }
  __syncthreads();

  // ---- series_decomp #1 -> bf16 chan-major ----
  {
    int t0 = tid * 4;
    float buf[28];
#pragma unroll
    for (int qd = 0; qd < 7; ++qd)
      *(float4*)&buf[qd * 4] = *(const float4*)&Csp[t0 + 4 + qd * 4];
    float s = 0.f;
#pragma unroll
    for (int m = 0; m < 25; ++m) s += buf[m];
    ushort4 o;
    o.x = f2bf(buf[12] - s * (1.0f / 25.0f));
    s += buf[25] - buf[0];
    o.y = f2bf(buf[13] - s * (1.0f / 25.0f));
    s += buf[26] - buf[1];
    o.z = f2bf(buf[14] - s * (1.0f / 25.0f));
    s += buf[27] - buf[2];
    o.w = f2bf(buf[15] - s * (1.0f / 25.0f));
    *(ushort4*)&xsbT[base + t0] = o;
  }
}

// ======== xsbT [c][t] bf16 -> xsb [t][c] bf16 ========
__global__ __launch_bounds__(256) void k_castT(const unsigned short* __restrict__ src,
                                               unsigned short* __restrict__ dst) {
  __shared__ unsigned short T[64][68];
  int b = blockIdx.z;
  int t0 = blockIdx.x * 64, c0 = blockIdx.y * 64;
  int tid = threadIdx.x;
  int lane = tid & 63, r4 = tid >> 6;
#pragma unroll
  for (int it = 0; it < 16; ++it) {
    int cl = it * 4 + r4;
    T[lane][cl] = src[((size_t)b * 512 + c0 + cl) * LL + t0 + lane];
  }
  __syncthreads();
  int tl = tid >> 2, cq = (tid & 3) * 16;
  unsigned short* d = dst + ((size_t)b * LL + t0 + tl) * 512 + c0 + cq;
#pragma unroll
  for (int j = 0; j < 16; j += 4) {
    ushort4 u;
    u.x = T[tl][cq + j]; u.y = T[tl][cq + j + 1];
    u.z = T[tl][cq + j + 2]; u.w = T[tl][cq + j + 3];
    *(ushort4*)&d[j] = u;
  }
}

// ======== final decomp: s2bT [c][t] bf16 -> out [t][c] f32 ========
#define DCH 32
__global__ __launch_bounds__(256) void k_decomp2T(const unsigned short* __restrict__ s2bT,
                                                  float* __restrict__ out) {
  __shared__ float T[DCH][289];
  int b = blockIdx.z, c0 = blockIdx.y * DCH, t0 = blockIdx.x * 256;
  int tid = threadIdx.x;
  {
    int row = tid >> 3, j0 = tid & 7;
    const unsigned short* src = s2bT + ((size_t)b * 512 + c0 + row) * LL;
#pragma unroll
    for (int i = 0; i < 9; ++i) {
      int col = (j0 + i * 8) * 4;
      int t = t0 - 16 + col;
      float4 v = make_float4(0.f, 0.f, 0.f, 0.f);
      if (t >= 0 && t < LL) {
        ushort4 u = *(const ushort4*)&src[t];
        v.x = bf2f(u.x); v.y = bf2f(u.y); v.z = bf2f(u.z); v.w = bf2f(u.w);
      }
      *(float4*)&T[row][col] = v;
    }
  }
  __syncthreads();
  int c = tid & 31, tg = tid >> 5;
  float sum = 0.f;
  int basec = tg * 32 + 4;
#pragma unroll
  for (int j = 0; j < 25; ++j) sum += T[c][basec + j];
  float* orow = out + ((size_t)b * LL + t0 + tg * 32) * 512 + c0 + c;
#pragma unroll 1
  for (int s = 0; s < 32; ++s) {
    float center = T[c][tg * 32 + 16 + s];
    orow[(size_t)s * 512] = center - sum * (1.f / 25.f);
    sum += T[c][basec + 25 + s] - T[c][basec + s];
  }
}

// ======== launch ========
extern "C" void kernel_launch(void* const* d_in, const int* in_sizes, int n_in,
                              void* d_out, int out_size, void* d_ws, size_t ws_size,
                              hipStream_t stream) {
  const float* x  = (const float*)d_in[0];
  const float* Wq = (const float*)d_in[1];
  const float* bq = (const float*)d_in[2];
  const float* Wk = (const float*)d_in[3];
  const float* bk = (const float*)d_in[4];
  const float* Wv = (const float*)d_in[5];
  const float* bv = (const float*)d_in[6];
  const float* W1 = (const float*)d_in[7];
  const float* b1 = (const float*)d_in[8];
  const float* W2 = (const float*)d_in[9];
  const float* b2 = (const float*)d_in[10];
  float* out = (float*)d_out;
  char* w = (char*)d_ws;

  unsigned short* xbT   = (unsigned short*)w;
  unsigned short* Qbf   = (unsigned short*)(w + (size_t)SZ * 4);
  unsigned short* Kbf   = Qbf + SZ;
  unsigned short* Vbf   = Kbf + SZ;
  unsigned short* WqkvT = (unsigned short*)(w + (size_t)SZ * 12);
  unsigned short* W1T   = WqkvT + 1536 * 512;
  unsigned short* W2T   = W1T + 512 * 512;
  float* bqkv           = (float*)(W2T + 512 * 512);
  unsigned short* xb    = (unsigned short*)(w + (size_t)SZ * 14);
  unsigned short* h1    = (unsigned short*)w;
  unsigned short* xsb   = (unsigned short*)(w + (size_t)SZ * 2);
  unsigned short* xsbT  = Qbf;
  unsigned short* s2bT  = Kbf;  // bf16 chan-major over dead K

  k_prep<<<dim3(1344), 256, 0, stream>>>(x, xbT, xb, Wq, Wk, Wv, W1, W2,
                                         bq, bk, bv, WqkvT, W1T, W2T, bqkv);

  k_mfma<0, 128><<<dim3(768), 256, 0, stream>>>(xb, WqkvT, bqkv, nullptr, Qbf, nullptr, 12);

  k_autocorr<<<dim3(NB * DD), 256, 0, stream>>>(Qbf, Kbf, Vbf, xbT, xsbT);

  k_castT<<<dim3(16, 8, NB), 256, 0, stream>>>(xsbT, xsb);

  k_mfma<1, 64><<<dim3(512), 256, 0, stream>>>(xsb, W1T, b1, nullptr, h1, nullptr, 4);
  k_mfma<2, 64><<<dim3(512), 256, 0, stream>>>(h1, W2T, b2, xsbT, s2bT, nullptr, 4);

  k_decomp2T<<<dim3(4, 16, NB), 256, 0, stream>>>(s2bT, out);
}